// Round 1
// baseline (79.484 us; speedup 1.0000x reference)
//
#include <hip/hip_runtime.h>
#include <math.h>

// SelfAttention (SAGAN-style, zero-init gamma gate)
//   B=4, C=128, H=W=64 -> N=4096, D=16
// out = gamma*sa + x.  gamma is a runtime input; when gamma==0 the output is
// exactly x (algebraic identity), so every kernel gates on the device-read
// gamma value: heavy kernels early-exit, finalize becomes a float4 copy.
// The full attention path is implemented and correct for gamma != 0.

namespace {

constexpr int kB = 4;
constexpr int kC = 128;
constexpr int kN = 4096;  // H*W
constexpr int kD = 16;

// out[b,o,n] = bias[o] + sum_c W[o,c] * x[b,c,n]      (1x1 conv as matmul)
__global__ void proj_kernel(const float* __restrict__ W,
                            const float* __restrict__ bias,
                            const float* __restrict__ x,
                            float* __restrict__ out,
                            int O,
                            const float* __restrict__ gamma) {
    if (gamma[0] == 0.0f) return;  // identity fast path: nothing to do
    const int total = kB * O * kN;
    for (int idx = blockIdx.x * blockDim.x + threadIdx.x; idx < total;
         idx += gridDim.x * blockDim.x) {
        const int n = idx % kN;
        const int o = (idx / kN) % O;
        const int b = idx / (kN * O);
        float acc = bias[o];
        const float* xp = x + (size_t)b * kC * kN + n;
        const float* wp = W + o * kC;
#pragma unroll 8
        for (int c = 0; c < kC; ++c)
            acc = fmaf(wp[c], xp[(size_t)c * kN], acc);
        out[idx] = acc;
    }
}

// Pass 1 of softmax: per (b, n) row of scores s[n,m] = <q[:,n], k[:,m]>,
// compute rowmax and rowsum (online, then block tree-reduce).
__global__ void stats_kernel(const float* __restrict__ q,
                             const float* __restrict__ k,
                             float* __restrict__ rowmax,
                             float* __restrict__ rowsum,
                             const float* __restrict__ gamma) {
    if (gamma[0] == 0.0f) return;
    __shared__ float sm[256];
    __shared__ float sl[256];
    const int rows = kB * kN;
    for (int row = blockIdx.x; row < rows; row += gridDim.x) {
        const int b = row / kN;
        const int n = row % kN;
        float qv[kD];
#pragma unroll
        for (int d = 0; d < kD; ++d)
            qv[d] = q[((size_t)(b * kD + d)) * kN + n];

        float m = -INFINITY, l = 0.0f;
        for (int mm = threadIdx.x; mm < kN; mm += blockDim.x) {
            const float* kp = k + (size_t)b * kD * kN + mm;
            float s = 0.0f;
#pragma unroll
            for (int d = 0; d < kD; ++d)
                s = fmaf(qv[d], kp[(size_t)d * kN], s);
            if (s > m) {
                l = l * expf(m - s) + 1.0f;  // expf(-inf)=0 on first hit
                m = s;
            } else {
                l += expf(s - m);
            }
        }
        sm[threadIdx.x] = m;
        sl[threadIdx.x] = l;
        __syncthreads();
        for (int off = blockDim.x / 2; off > 0; off >>= 1) {
            if ((int)threadIdx.x < off) {
                const float m1 = sm[threadIdx.x], l1 = sl[threadIdx.x];
                const float m2 = sm[threadIdx.x + off], l2 = sl[threadIdx.x + off];
                const float mx = fmaxf(m1, m2);
                float ln = 0.0f;
                if (m1 > -INFINITY) ln += l1 * expf(m1 - mx);
                if (m2 > -INFINITY) ln += l2 * expf(m2 - mx);
                sm[threadIdx.x] = mx;
                sl[threadIdx.x] = ln;
            }
            __syncthreads();
        }
        if (threadIdx.x == 0) {
            rowmax[row] = sm[0];
            rowsum[row] = sl[0];
        }
        __syncthreads();
    }
}

// Pass 2: sa[c,m] = sum_n v[c,n] * exp(s[n,m]-rowmax[n]) / rowsum[n]
// One 128-thread block per (b, m) column (grid-stride); thread = channel c.
__global__ void sa_kernel(const float* __restrict__ q,
                          const float* __restrict__ k,
                          const float* __restrict__ v,
                          const float* __restrict__ rowmax,
                          const float* __restrict__ rowsum,
                          float* __restrict__ sa,
                          const float* __restrict__ gamma) {
    if (gamma[0] == 0.0f) return;
    __shared__ float kv[kD];
    __shared__ float w[128];
    const int cols = kB * kN;
    for (int col = blockIdx.x; col < cols; col += gridDim.x) {
        const int b = col / kN;
        const int m = col % kN;
        if ((int)threadIdx.x < kD)
            kv[threadIdx.x] = k[((size_t)(b * kD + threadIdx.x)) * kN + m];
        __syncthreads();
        float kreg[kD];
#pragma unroll
        for (int d = 0; d < kD; ++d) kreg[d] = kv[d];

        const int c = threadIdx.x;
        float acc = 0.0f;
        for (int n0 = 0; n0 < kN; n0 += 128) {
            const int n = n0 + threadIdx.x;
            const float* qp = q + (size_t)b * kD * kN + n;
            float s = 0.0f;
#pragma unroll
            for (int d = 0; d < kD; ++d)
                s = fmaf(kreg[d], qp[(size_t)d * kN], s);
            __syncthreads();  // protect w[] from previous tile's readers
            w[threadIdx.x] = expf(s - rowmax[b * kN + n]) / rowsum[b * kN + n];
            __syncthreads();
            const float* vp = v + ((size_t)(b * kC + c)) * kN + n0;
#pragma unroll 8
            for (int j = 0; j < 128; ++j)
                acc = fmaf(w[j], vp[j], acc);
        }
        sa[((size_t)(b * kC + c)) * kN + m] = acc;
        __syncthreads();  // before next col overwrites kv
    }
}

// out = x + gamma*sa; degenerates to a pure float4 copy when gamma == 0.
__global__ void finalize_kernel(const float* __restrict__ x,
                                const float* __restrict__ sa,
                                const float* __restrict__ gamma,
                                float* __restrict__ out) {
    const float g = gamma[0];
    const size_t total4 = (size_t)kB * kC * kN / 4;
    const size_t stride = (size_t)gridDim.x * blockDim.x;
    size_t i = (size_t)blockIdx.x * blockDim.x + threadIdx.x;
    const float4* x4 = (const float4*)x;
    float4* o4 = (float4*)out;
    if (g == 0.0f) {
        for (; i < total4; i += stride) o4[i] = x4[i];
    } else {
        const float4* s4 = (const float4*)sa;
        for (; i < total4; i += stride) {
            const float4 a = x4[i];
            const float4 s = s4[i];
            o4[i] = make_float4(fmaf(g, s.x, a.x), fmaf(g, s.y, a.y),
                                fmaf(g, s.z, a.z), fmaf(g, s.w, a.w));
        }
    }
}

}  // namespace

extern "C" void kernel_launch(void* const* d_in, const int* in_sizes, int n_in,
                              void* d_out, int out_size, void* d_ws, size_t ws_size,
                              hipStream_t stream) {
    const float* x     = (const float*)d_in[0];
    const float* Wq    = (const float*)d_in[1];
    const float* bq    = (const float*)d_in[2];
    const float* Wk    = (const float*)d_in[3];
    const float* bk    = (const float*)d_in[4];
    const float* Wv    = (const float*)d_in[5];
    const float* bv    = (const float*)d_in[6];
    const float* gamma = (const float*)d_in[7];
    float* out = (float*)d_out;

    // Workspace layout (floats); only touched when gamma != 0.
    float* q      = (float*)d_ws;                    // B*D*N   = 262144
    float* k      = q + (size_t)kB * kD * kN;        // B*D*N   = 262144
    float* v      = k + (size_t)kB * kD * kN;        // B*C*N   = 2097152
    float* rowmax = v + (size_t)kB * kC * kN;        // B*N     = 16384
    float* rowsum = rowmax + (size_t)kB * kN;        // B*N     = 16384
    float* sa     = rowsum + (size_t)kB * kN;        // B*C*N   = 2097152

    proj_kernel<<<512, 256, 0, stream>>>(Wq, bq, x, q, kD, gamma);
    proj_kernel<<<512, 256, 0, stream>>>(Wk, bk, x, k, kD, gamma);
    proj_kernel<<<2048, 256, 0, stream>>>(Wv, bv, x, v, kC, gamma);
    stats_kernel<<<1024, 256, 0, stream>>>(q, k, rowmax, rowsum, gamma);
    sa_kernel<<<2048, 128, 0, stream>>>(q, k, v, rowmax, rowsum, sa, gamma);
    finalize_kernel<<<2048, 256, 0, stream>>>(x, sa, gamma, out);
}